// Round 7
// baseline (1598.180 us; speedup 1.0000x reference)
//
#include <hip/hip_runtime.h>
#include <hip/hip_bf16.h>

// B=256, L=2048, H=128, V=32000, THR=0.4, LN_EPS=1e-5. All fp32.
// Htab2 row (RS=136 floats): [0:64)=h lo, [68:132)=h hi, [132]=kk, [133]=inv.
// Scan v7: PAIRED steps (rank-2 update). Per pair: vp_a=M*ka, vp_b=M*kb, d=ka.kb
// pre-barrier; reductions {|e_a|^2, |c|^2, c.e_a} in ONE barrier; gate_b from
// closed form. True double-buffered k regs (pin BEFORE update), 4-slot DMA ring.

#define BB 256
#define LL 2048
#define HH 128
#define VV 32000
#define RS 136

typedef float f32x2 __attribute__((ext_vector_type(2)));

__device__ __forceinline__ void dma16(const float* g, float* l) {
  __builtin_amdgcn_global_load_lds(
      (const __attribute__((address_space(1))) void*)g,
      (__attribute__((address_space(3))) void*)l,
      16, 0, 0);
}

template <int CTRL>
__device__ __forceinline__ float dppadd(float x) {
  int y = __builtin_amdgcn_update_dpp(0, __float_as_int(x), CTRL, 0xF, 0xF, true);
  return x + __int_as_float(y);
}

__device__ __forceinline__ void pkfma(f32x2& d, f32x2 a, f32x2 b) {
  asm("v_pk_fma_f32 %0, %1, %2, %0" : "+v"(d) : "v"(a), "v"(b));
}

__device__ __forceinline__ void barrier_lgkm() {
  asm volatile("s_waitcnt lgkmcnt(0)\n\ts_barrier" ::: "memory");
}
__device__ __forceinline__ void wait_vm0() {
  asm volatile("s_waitcnt vmcnt(0)" ::: "memory");
}

// k-pair register set: a/b vectors (own 64 cols as 32 f32x2), scalars.
struct KSet {
  f32x2 a[32], b[32];
  float kia, kkA, invA, kib, kkB, invB;
};

__device__ __forceinline__ void pin(KSet& K) {
#pragma unroll
  for (int m = 0; m < 32; ++m) asm volatile("" : "+v"(K.a[m]));
#pragma unroll
  for (int m = 0; m < 32; ++m) asm volatile("" : "+v"(K.b[m]));
  asm volatile("" : "+v"(K.kia), "+v"(K.kkA), "+v"(K.invA));
  asm volatile("" : "+v"(K.kib), "+v"(K.kkB), "+v"(K.invB));
}

// ---------------------------------------------------------------------------
// Kernel A (unchanged from r6)
// ---------------------------------------------------------------------------
__global__ __launch_bounds__(256, 1) void build_htab_kernel(
    const float* __restrict__ embed,
    const float* __restrict__ W1,
    const float* __restrict__ b1,
    const float* __restrict__ W2,
    const float* __restrict__ b2,
    const float* __restrict__ gamma,
    const float* __restrict__ beta,
    float* __restrict__ Htab2)
{
  const int tid = threadIdx.x;
  const int j   = tid & 127;
  const int h2  = tid >> 7;

  float w1r[128];
#pragma unroll
  for (int m = 0; m < 128; ++m) w1r[m] = W1[m * 256 + tid];

  const float b1n = b1[tid];
  const float b2j = b2[j];
  const float gj  = gamma[j];
  const float bj  = beta[j];

  __shared__ __align__(16) float4 w2q[64][128];
  __shared__ __align__(16) float e_s[128];
  __shared__ __align__(16) float a_s[256];
  __shared__ float p_s[2][128];
  __shared__ float red[8];

  for (int idx = tid; idx < 8192; idx += 256) {
    int n4 = idx >> 7, jj = idx & 127;
    float4 w;
    w.x = W2[(size_t)(4 * n4 + 0) * 128 + jj];
    w.y = W2[(size_t)(4 * n4 + 1) * 128 + jj];
    w.z = W2[(size_t)(4 * n4 + 2) * 128 + jj];
    w.w = W2[(size_t)(4 * n4 + 3) * 128 + jj];
    w2q[n4][jj] = w;
  }
  __syncthreads();

  for (int v = blockIdx.x; v < VV; v += gridDim.x) {
    if (tid < 128) e_s[tid] = embed[(size_t)v * 128 + tid];
    __syncthreads();

    float acc[4] = {b1n, 0.f, 0.f, 0.f};
#pragma unroll
    for (int q = 0; q < 32; ++q) {
      float4 ev = *(const float4*)&e_s[4 * q];
      float t = ev.x * w1r[4 * q + 0];
      t = fmaf(ev.y, w1r[4 * q + 1], t);
      t = fmaf(ev.z, w1r[4 * q + 2], t);
      t = fmaf(ev.w, w1r[4 * q + 3], t);
      acc[q & 3] += t;
    }
    float a = fmaxf((acc[0] + acc[1]) + (acc[2] + acc[3]), 0.0f);
    a_s[tid] = a;
    __syncthreads();

    float p0 = 0.f, p1 = 0.f, p2v = 0.f, p3 = 0.f;
#pragma unroll
    for (int q = 0; q < 32; ++q) {
      int n4 = h2 * 32 + q;
      float4 av = *(const float4*)&a_s[4 * n4];
      float4 wq = w2q[n4][j];
      p0 = fmaf(av.x, wq.x, p0);
      p1 = fmaf(av.y, wq.y, p1);
      p2v = fmaf(av.z, wq.z, p2v);
      p3 = fmaf(av.w, wq.w, p3);
    }
    p_s[h2][j] = (p0 + p1) + (p2v + p3);
    __syncthreads();

    float y = 0.0f;
    if (tid < 128) {
      float ff = p_s[0][tid] + p_s[1][tid] + b2j;
      y = e_s[tid] + ff;
    }
    float s1 = y, s2 = y * y;
    s1 = dppadd<0xB1>(s1);  s2 = dppadd<0xB1>(s2);
    s1 = dppadd<0x4E>(s1);  s2 = dppadd<0x4E>(s2);
    s1 = dppadd<0x141>(s1); s2 = dppadd<0x141>(s2);
    s1 = dppadd<0x140>(s1); s2 = dppadd<0x140>(s2);
    s1 = dppadd<0x142>(s1); s2 = dppadd<0x142>(s2);
    s1 = dppadd<0x143>(s1); s2 = dppadd<0x143>(s2);
    if (tid < 128 && (tid & 63) == 63) {
      red[tid >> 6] = s1;
      red[2 + (tid >> 6)] = s2;
    }
    __syncthreads();
    float mu = (red[0] + red[1]) * (1.0f / 128.0f);
    float ms = (red[2] + red[3]) * (1.0f / 128.0f);
    float var = ms - mu * mu;
    float hv = 0.0f;
    if (tid < 128) {
      float dy = y - mu;
      hv = dy * (1.0f / sqrtf(var + 1e-5f)) * gj + bj;
      int ofs = tid + ((tid >> 6) << 2);
      Htab2[(size_t)v * RS + ofs] = hv;
    }
    float q2 = hv * hv;
    q2 = dppadd<0xB1>(q2);
    q2 = dppadd<0x4E>(q2);
    q2 = dppadd<0x141>(q2);
    q2 = dppadd<0x140>(q2);
    q2 = dppadd<0x142>(q2);
    q2 = dppadd<0x143>(q2);
    if (tid < 128 && (tid & 63) == 63) red[4 + (tid >> 6)] = q2;
    __syncthreads();
    if (tid == 0) {
      float kk = red[4] + red[5];
      Htab2[(size_t)v * RS + 132] = kk;
      Htab2[(size_t)v * RS + 133] = 1.0f / (kk + 1e-6f);
    }
    __syncthreads();
  }
}

// ---------------------------------------------------------------------------
// Kernel B: paired-step scan. 256 blocks x 256 threads, 1 block/CU.
// ---------------------------------------------------------------------------
__global__ __launch_bounds__(256, 1) void scan_kernel(
    const int* __restrict__ seq,
    const float* __restrict__ Htab2,
    const float* __restrict__ Wrp,
    const float* __restrict__ brp,
    float* __restrict__ rr)
{
  const int b     = blockIdx.x;
  const int tid   = threadIdx.x;
  const int i     = tid >> 1;
  const int half  = tid & 1;
  const int lane  = tid & 63;
  const int wv    = tid >> 6;
  const int iofs  = i + ((i >> 6) << 2);
  const int kbase = half * 68;

  __shared__ int seq_s[LL];
  __shared__ __align__(16) float slots[4][RS];
  __shared__ __align__(16) float red2[3][4];   // [scalar][wave]
  __shared__ __align__(16) float r_s[128];
  __shared__ float p2_s[2][128];

  {
    int t0 = seq[(size_t)b * LL + 0];
    int t1 = seq[(size_t)b * LL + 1];
    if (lane < 34) {
      dma16(Htab2 + (size_t)t0 * RS + lane * 4, &slots[0][0]);
      dma16(Htab2 + (size_t)t1 * RS + lane * 4, &slots[1][0]);
    }
  }
  for (int t = tid; t < LL; t += 256) seq_s[t] = seq[(size_t)b * LL + t];
  __syncthreads();

  f32x2 M2[32];
#pragma unroll
  for (int m = 0; m < 32; ++m) M2[m] = f32x2{0.f, 0.f};

  KSet KA, KB;

  auto load_set = [&](KSet& K, int sa, int sb) {
    const float4* pa = (const float4*)&slots[sa][kbase];
    const float4* pb = (const float4*)&slots[sb][kbase];
#pragma unroll
    for (int m = 0; m < 16; ++m) {
      float4 ta = pa[m];
      K.a[2 * m]     = f32x2{ta.x, ta.y};
      K.a[2 * m + 1] = f32x2{ta.z, ta.w};
      float4 tb = pb[m];
      K.b[2 * m]     = f32x2{tb.x, tb.y};
      K.b[2 * m + 1] = f32x2{tb.z, tb.w};
    }
    K.kia = slots[sa][iofs];
    K.kib = slots[sb][iofs];
    float2 va = *(const float2*)&slots[sa][132];
    float2 vb = *(const float2*)&slots[sb][132];
    K.kkA = va.x; K.invA = va.y;
    K.kkB = vb.x; K.invB = vb.y;
  };

  load_set(KA, 0, 1);
  pin(KA);

  // pair-iter n processes t=2n,2n+1 using Kc; DMAs k(2n+2),k(2n+3) into the
  // other slot-pair; refills Kn from it at the end. mode 0 = steady, 1 = last.
  auto pair_step = [&](KSet& Kc, KSet& Kn, int n, int mode) {
    int sd = ((n + 1) & 1) * 2;
    {
      int ta = seq_s[2 * n + 2], tb = seq_s[2 * n + 3];
      if (lane < 34) {
        dma16(Htab2 + (size_t)ta * RS + lane * 4, &slots[sd][0]);
        dma16(Htab2 + (size_t)tb * RS + lane * 4, &slots[sd + 1][0]);
      }
    }
    // vp_a, vp_b, d (own 64 cols), interleaved for ILP
    f32x2 aa{0.f,0.f}, ab{0.f,0.f}, ba{0.f,0.f}, bb{0.f,0.f}, dd{0.f,0.f}, de{0.f,0.f};
#pragma unroll
    for (int m = 0; m < 16; ++m) {
      pkfma(aa, Kc.a[2 * m],     M2[2 * m]);
      pkfma(ab, Kc.a[2 * m + 1], M2[2 * m + 1]);
      pkfma(ba, Kc.b[2 * m],     M2[2 * m]);
      pkfma(bb, Kc.b[2 * m + 1], M2[2 * m + 1]);
      pkfma(dd, Kc.a[2 * m],     Kc.b[2 * m]);
      pkfma(de, Kc.a[2 * m + 1], Kc.b[2 * m + 1]);
    }
    float vpa = (aa.x + aa.y) + (ab.x + ab.y);
    float vpb = (ba.x + ba.y) + (bb.x + bb.y);
    float d   = (dd.x + dd.y) + (de.x + de.y);
    vpa = dppadd<0xB1>(vpa);
    vpb = dppadd<0xB1>(vpb);
    d   = dppadd<0xB1>(d);                    // full dot, all lanes
    float ea = fmaf(-vpa, Kc.invA, Kc.kia);
    float c  = fmaf(-vpb, Kc.invB, Kc.kib);
    // three interleaved 5-level trees (rows counted once; pair-duplicates skipped)
    float sE = ea * ea, sC = c * c, sX = c * ea;
    sE = dppadd<0x4E>(sE);  sC = dppadd<0x4E>(sC);  sX = dppadd<0x4E>(sX);
    sE = dppadd<0x141>(sE); sC = dppadd<0x141>(sC); sX = dppadd<0x141>(sX);
    sE = dppadd<0x140>(sE); sC = dppadd<0x140>(sC); sX = dppadd<0x140>(sX);
    sE = dppadd<0x142>(sE); sC = dppadd<0x142>(sC); sX = dppadd<0x142>(sX);
    sE = dppadd<0x143>(sE); sC = dppadd<0x143>(sC); sX = dppadd<0x143>(sX);
    if (lane == 63) {
      red2[0][wv] = sE;
      red2[1][wv] = sC;
      red2[2][wv] = sX;
    }
    barrier_lgkm();                           // lgkm drain + barrier (no vmcnt)

    float4 rE = *(const float4*)red2[0];
    float4 rC = *(const float4*)red2[1];
    float4 rX = *(const float4*)red2[2];

    wait_vm0();                               // this iter's DMAs (issued ~a full
    load_set(Kn, sd, sd + 1);                 //  pair ago in wall time) landed
    pin(Kn);                                  // pin BEFORE update: forces dbuf

    float SE = (rE.x + rE.y) + (rE.z + rE.w); // ||e_a||^2
    float SC = (rC.x + rC.y) + (rC.z + rC.w); // ||c||^2
    float SX = (rX.x + rX.y) + (rX.z + rX.w); // c . e_a
    float ga = (SE > 0.16f * Kc.kkA) ? 1.0f : 0.0f;
    float hb = ga * d * Kc.invB;
    float eb = fmaf(-hb, ea, c);
    float SEB = fmaf(hb * hb, SE, fmaf(-2.0f * hb, SX, SC));  // ||e_b||^2
    float gea = ga * ea;
    float geb = (SEB > 0.16f * Kc.kkB) ? eb : 0.0f;
    f32x2 va{gea, gea}, vb{geb, geb};
#pragma unroll
    for (int m = 0; m < 32; ++m) {
      pkfma(M2[m], va, Kc.a[m]);
      pkfma(M2[m], vb, Kc.b[m]);
    }
    (void)mode;
  };

  // 1023 pair-iters: t = 0..2045
  for (int n = 0; n < 511; ++n) {
    pair_step(KA, KB, 2 * n, 0);
    pair_step(KB, KA, 2 * n + 1, 0);
  }
  pair_step(KA, KB, 1022, 1);   // refills KB = (k2046, k2047)

  // tail single step t=2046 with KB.a
  {
    f32x2 aa{0.f,0.f}, ab{0.f,0.f};
#pragma unroll
    for (int m = 0; m < 16; ++m) {
      pkfma(aa, KB.a[2 * m],     M2[2 * m]);
      pkfma(ab, KB.a[2 * m + 1], M2[2 * m + 1]);
    }
    float vp = (aa.x + aa.y) + (ab.x + ab.y);
    vp = dppadd<0xB1>(vp);
    float e = fmaf(-vp, KB.invA, KB.kia);
    float s = e * e;
    s = dppadd<0x4E>(s);
    s = dppadd<0x141>(s);
    s = dppadd<0x140>(s);
    s = dppadd<0x142>(s);
    s = dppadd<0x143>(s);
    if (lane == 63) red2[0][wv] = s;
    __syncthreads();
    float4 rv = *(const float4*)red2[0];
    float ne2 = (rv.x + rv.y) + (rv.z + rv.w);
    float ge = (ne2 > 0.16f * KB.kkA) ? e : 0.0f;
    f32x2 ev{ge, ge};
#pragma unroll
    for (int m = 0; m < 32; ++m) pkfma(M2[m], ev, KB.a[m]);
  }

  // r = M_fin @ k_2047 (KB.b)
  {
    f32x2 aa{0.f,0.f}, ab{0.f,0.f};
#pragma unroll
    for (int m = 0; m < 16; ++m) {
      pkfma(aa, KB.b[2 * m],     M2[2 * m]);
      pkfma(ab, KB.b[2 * m + 1], M2[2 * m + 1]);
    }
    float vp = (aa.x + aa.y) + (ab.x + ab.y);
    vp = dppadd<0xB1>(vp);
    if (half == 0) r_s[i] = vp;
  }
  __syncthreads();

  // rr[b,:] = r @ Wrp + brp
  const int j  = tid & 127;
  const int h2 = tid >> 7;
  float pac[2] = {0.f, 0.f};
#pragma unroll
  for (int m = 0; m < 64; ++m) {
    pac[m & 1] = fmaf(r_s[h2 * 64 + m],
                      Wrp[(size_t)(h2 * 64 + m) * 128 + j], pac[m & 1]);
  }
  p2_s[h2][j] = pac[0] + pac[1];
  __syncthreads();
  if (tid < 128) {
    rr[(size_t)b * 128 + tid] = p2_s[0][tid] + p2_s[1][tid] + brp[tid];
  }
}

// ---------------------------------------------------------------------------
// Kernel C (unchanged)
// ---------------------------------------------------------------------------
__global__ __launch_bounds__(256, 1) void out_kernel(
    const float* __restrict__ rr,
    const float* __restrict__ Wout,
    const float* __restrict__ bout,
    float* __restrict__ out)
{
  const int tid = threadIdx.x;
  const int v = blockIdx.x * 64 + (tid & 63);
  const int bg = tid >> 6;
  const int b0 = blockIdx.y * 64;

  __shared__ float4 rs4[64][32];
  for (int idx = tid; idx < 2048; idx += 256) {
    int bb = idx >> 5, q = idx & 31;
    rs4[bb][q] = ((const float4*)rr)[(size_t)(b0 + bb) * 32 + q];
  }
  __syncthreads();

  float acc[16];
#pragma unroll
  for (int m = 0; m < 16; ++m) acc[m] = 0.0f;

  for (int h4 = 0; h4 < 32; ++h4) {
    float w0 = Wout[(size_t)(4 * h4 + 0) * VV + v];
    float w1 = Wout[(size_t)(4 * h4 + 1) * VV + v];
    float w2 = Wout[(size_t)(4 * h4 + 2) * VV + v];
    float w3 = Wout[(size_t)(4 * h4 + 3) * VV + v];
#pragma unroll
    for (int m = 0; m < 16; ++m) {
      float4 rv = rs4[bg * 16 + m][h4];
      float t = rv.x * w0;
      t = fmaf(rv.y, w1, t);
      t = fmaf(rv.z, w2, t);
      t = fmaf(rv.w, w3, t);
      acc[m] += t;
    }
  }
  float bo = bout[v];
#pragma unroll
  for (int m = 0; m < 16; ++m) {
    out[(size_t)(b0 + bg * 16 + m) * VV + v] = acc[m] + bo;
  }
}

// ---------------------------------------------------------------------------
extern "C" void kernel_launch(void* const* d_in, const int* in_sizes, int n_in,
                              void* d_out, int out_size, void* d_ws, size_t ws_size,
                              hipStream_t stream)
{
  const int* seq      = (const int*)d_in[0];
  const float* embed  = (const float*)d_in[1];
  const float* W1     = (const float*)d_in[2];
  const float* b1     = (const float*)d_in[3];
  const float* W2     = (const float*)d_in[4];
  const float* b2     = (const float*)d_in[5];
  const float* gamma  = (const float*)d_in[6];
  const float* beta   = (const float*)d_in[7];
  const float* Wrp    = (const float*)d_in[8];
  const float* brp    = (const float*)d_in[9];
  const float* Wout   = (const float*)d_in[10];
  const float* bout   = (const float*)d_in[11];
  float* out          = (float*)d_out;

  char* ws = (char*)d_ws;
  float* Htab2 = (float*)ws;                         // 17,408,000 B
  float* rr    = (float*)(ws + 17408000);            //    131,072 B

  hipLaunchKernelGGL(build_htab_kernel, dim3(256), dim3(256), 0, stream,
                     embed, W1, b1, W2, b2, gamma, beta, Htab2);
  hipLaunchKernelGGL(scan_kernel, dim3(BB), dim3(256), 0, stream,
                     seq, Htab2, Wrp, brp, rr);
  hipLaunchKernelGGL(out_kernel, dim3(VV / 64, 4), dim3(256), 0, stream,
                     rr, Wout, bout, out);
}